// Round 2
// baseline (114.609 us; speedup 1.0000x reference)
//
#include <hip/hip_runtime.h>
#include <hip/hip_cooperative_groups.h>
#include <math.h>

namespace cg = cooperative_groups;

#define N_BOXES 10647
#define NUM_CLASSES 80
#define MAX_BOXES 20
#define IOU_T 0.1f
#define SCORE_T 0.3f

#define NT 1024
#define NWAVES (NT / 64)
#define KP 11      // ceil(N_BOXES / NT): per-thread candidate slots
#define WCAP 128   // window capacity (LDS)
#define TGT 96     // target window size (expected examine ~40 for 20 keeps)

// Transpose tiling (phase 1): 64-row tiles -> 167 blocks (latency-bound,
// wide coverage) + 6 boxes-copy blocks. All blocks join the grid sync.
#define TROWS 64
#define TBLOCKS 167     // ceil(10647 / 64)
#define CPBLOCKS 6      // boxes-copy blocks
#define GRID_BLOCKS (TBLOCKS + CPBLOCKS)

// Output layout (all float32, concatenated):
//   [0)      boxes copy        N_BOXES*4               = 42588
//   [42588)  scores transposed NUM_CLASSES*N_BOXES     = 851760
//   [894348) nms_final         NUM_CLASSES*MAX_BOXES*3 = 4800
#define OUT_OFF_SCORES (N_BOXES * 4)
#define OUT_OFF_NMS (N_BOXES * 4 + NUM_CLASSES * N_BOXES)

// R15: the R14 fused-strided experiment showed the strided column gather
// costs MORE than the whole transpose kernel + a launch. Keep both proven
// coalesced phases, but replace the kernel boundary (launch + full drain)
// with a cooperative grid sync inside ONE dispatch. 173 blocks x 1024 thr
// = 1 block/CU (VGPR-bound) < 256 co-resident bound.
#define FOR_K(OP) OP(0) OP(1) OP(2) OP(3) OP(4) OP(5) OP(6) OP(7) OP(8) OP(9) OP(10)

// Reference-exact IoU>T test (individually rounded float32 ops; inter==0 =>
// reference IoU is 0 => not suppressed, divide skipped). First box is the
// SELECTED box (reference's area1 = selected's area, added first).
__device__ __forceinline__ bool iou_gt(float jy1, float jx1, float jy2,
                                       float jx2, float area_j, float4 b) {
    float ty = fmaxf(jy1, b.x);
    float tx = fmaxf(jx1, b.y);
    float by = fminf(jy2, b.z);
    float bx = fminf(jx2, b.w);
    float dy = fmaxf(__fsub_rn(by, ty), 0.0f);
    float dx = fmaxf(__fsub_rn(bx, tx), 0.0f);
    float inter = __fmul_rn(dy, dx);
    if (!(inter > 0.0f)) return false;
    float area_i = __fmul_rn(__fsub_rn(b.z, b.x), __fsub_rn(b.w, b.y));
    float uni = __fsub_rn(__fadd_rn(area_j, area_i), inter);
    float iou = (uni > 0.0f) ? __fdiv_rn(inter, uni) : 0.0f;
    return iou > IOU_T;
}

// ---------------------------------------------------------------------------
// Cooperative fused kernel:
//   phase 1 (all blocks): coalesced transpose tiles / boxes copy
//   grid sync
//   phase 2 (blocks 0..79): per-class NMS, coalesced transposed-column read
// ---------------------------------------------------------------------------
__global__ __launch_bounds__(NT) void fused_coop_kernel(
    const float* __restrict__ boxes, const float* __restrict__ scores,
    float* __restrict__ out) {
    const int tid = threadIdx.x;
    const int b = blockIdx.x;
    const int wave = tid >> 6;
    const int lane = tid & 63;

    // ---- LDS: phase-1 tile + phase-2 NMS state (disjoint lifetimes but
    // kept separate; total ~37 KB, still 1 block/CU either way).
    __shared__ float lds_t[TROWS * 81];             // 20.7 KB transpose tile
    __shared__ int s_hist[2048];                    // 8 KB
    __shared__ unsigned long long s_k[WCAP];        // 1 KB window keys
    __shared__ float4 s_b4[WCAP];                   // 2 KB window boxes
    __shared__ unsigned long long s_ks[WCAP];       // 1 KB sorted keys
    __shared__ float4 s_bs[WCAP];                   // 2 KB sorted boxes
    __shared__ __align__(16) unsigned long long s_mask[WCAP][2];  // 2 KB
    __shared__ unsigned long long s_rk[2][NWAVES];  // fallback reduce
    __shared__ int s_out[MAX_BOXES];
    __shared__ int s_bstar, s_total, s_cnt, s_nsel;

    // ---- Phase 1: transpose / boxes copy ----
    if (b >= TBLOCKS) {
        for (int q = (b - TBLOCKS) * NT + tid; q < N_BOXES;
             q += CPBLOCKS * NT) {
            ((float4*)out)[q] = ((const float4*)boxes)[q];
        }
    } else {
        const int r0 = b * TROWS;
        const int nr = min(TROWS, N_BOXES - r0);

        // Read: contiguous chunk scores[r0*80 .. (r0+nr)*80), float4 loads.
        const int nq = nr * 20;  // 80 floats/row = 20 float4/row
        for (int q = tid; q < nq; q += NT) {
            const int r = q / 20;
            const int c4 = (q - r * 20) * 4;
            float4 v = *(const float4*)(scores + (r0 + r) * NUM_CLASSES + c4);
            float* dst = &lds_t[r * 81 + c4];
            dst[0] = v.x;
            dst[1] = v.y;
            dst[2] = v.z;
            dst[3] = v.w;
        }
        __syncthreads();

        // Write: each wave writes 64 consecutive rows of one class (256 B
        // contiguous per store instruction), 5 classes per thread.
        const int r = tid & (TROWS - 1);
        const int chi = tid >> 6;  // 0..15
        if (r < nr) {
            #pragma unroll
            for (int p = 0; p < 5; ++p) {
                const int c = p * 16 + chi;
                out[OUT_OFF_SCORES + c * N_BOXES + r0 + r] = lds_t[r * 81 + c];
            }
        }
    }

    // NMS LDS init overlaps the tail of phase 1 (local, no dependency).
    if (tid < MAX_BOXES) s_out[tid] = -1;
    if (tid == 0) { s_cnt = 0; s_nsel = 0; }
    s_hist[tid] = 0;
    s_hist[tid + NT] = 0;

    // ---- grid-wide sync: all transposed columns visible device-wide ----
    cg::this_grid().sync();

    if (b >= NUM_CLASSES) return;
    const int c = b;

    const float4* boxes4 = (const float4*)boxes;
    const float* col = out + OUT_OFF_SCORES + c * N_BOXES;  // contiguous

    // ---- Phase A: coalesced column read -> keys + histogram.
    // key = (score_bits << 32) | (0xFFFFFFFF - idx): u64 max == max score,
    // tie -> lowest index (jnp.argmax first-occurrence). 0 = invalid.
#define DECL_K(k) unsigned long long k_##k = 0;
    FOR_K(DECL_K)
#undef DECL_K
#define BUILD_K(k)                                                     \
    {                                                                  \
        int i = tid + (k)*NT;                                          \
        if (i < N_BOXES) {                                             \
            float v = col[i];                                          \
            if (v >= SCORE_T) {                                        \
                unsigned int vb = __float_as_uint(v);                  \
                k_##k = ((unsigned long long)vb << 32) |               \
                        (0xFFFFFFFFu - (unsigned int)i);               \
                atomicAdd(&s_hist[(vb - 0x3E800000u) >> 13], 1);       \
            }                                                          \
        }                                                              \
    }
    FOR_K(BUILD_K)
#undef BUILD_K
    __syncthreads();

    // ---- Phase B (wave 0, fully parallel): b* = max bin with
    // suffix-count >= TGT (0 if total < TGT).
    if (wave == 0) {
        int lsum = 0;
        #pragma unroll
        for (int t = 0; t < 32; ++t) {
            int bb = (t + lane) & 31;  // rotate -> conflict-free banks
            lsum += s_hist[lane * 32 + bb];
        }
        int S = lsum;  // inclusive suffix over lanes (lane l: bins >= l*32)
        #pragma unroll
        for (int off = 1; off < 64; off <<= 1) {
            int up = __shfl_down(S, off);
            if (lane + off < 64) S += up;
        }
        unsigned long long mk = __ballot(S >= TGT);
        int bstar = 0;
        if (mk != 0) {
            const int L = 63 - __builtin_clzll(mk);
            const int S_L = __shfl(S, L);
            const int lsum_L = __shfl(lsum, L);
            const int S_above = S_L - lsum_L;  // suffix above lane L's bins
            int h = (lane < 32) ? s_hist[L * 32 + lane] : 0;
            int sfx = h;
            #pragma unroll
            for (int off = 1; off < 64; off <<= 1) {
                int up = __shfl_down(sfx, off);
                if (lane + off < 64) sfx += up;
            }
            unsigned long long sel = __ballot(sfx + S_above >= TGT);
            bstar = L * 32 + (63 - __builtin_clzll(sel));
        }
        if (lane == 0) {
            s_bstar = bstar;
            s_total = S;  // lane0 inclusive suffix == grand total
        }
    }
    __syncthreads();

    const unsigned int tbits = 0x3E800000u + ((unsigned int)s_bstar << 13);

    // ---- Phase C: compact window (score_bits >= tbits) into LDS ----
#define COMPACT_K(k)                                                    \
    {                                                                   \
        bool p = (k_##k != 0) &&                                        \
                 ((unsigned int)(k_##k >> 32) >= tbits);                \
        unsigned long long m = __ballot(p);                             \
        int basew = 0;                                                  \
        if (lane == 0 && m) basew = atomicAdd(&s_cnt, __popcll(m));     \
        basew = __shfl(basew, 0);                                       \
        if (p) {                                                        \
            int pos = basew + __popcll(m & ((1ull << lane) - 1ull));    \
            if (pos < WCAP) {                                           \
                s_k[pos] = k_##k;                                       \
                s_b4[pos] = boxes4[0xFFFFFFFFu - (unsigned int)k_##k];  \
            }                                                           \
        }                                                               \
    }
    FOR_K(COMPACT_K)
#undef COMPACT_K
    __syncthreads();

    const int wcnt = s_cnt;
    const bool overflow = (wcnt > WCAP);  // pathological ties only

    // ---- Phase D1: parallel rank sort of the window (threads 0..wcnt).
    // rank_i = #{j : key_j > key_i}; keys unique -> permutation. Broadcast
    // LDS reads, conflict-free.
    if (!overflow && tid < wcnt) {
        const unsigned long long mykey = s_k[tid];
        const float4 mybox = s_b4[tid];
        int rank = 0;
        for (int j = 0; j < wcnt; ++j) rank += (s_k[j] > mykey) ? 1 : 0;
        s_ks[rank] = mykey;
        s_bs[rank] = mybox;
    }
    __syncthreads();

    // ---- Phase D2: parallel suppression bit-matrix. Task t = (row,chunk):
    // lane computes iou_gt(row, chunk*64+lane); one ballot per task; all 16
    // waves work concurrently. Row = selected-box role (reference op order).
    if (!overflow) {
        const int ntask = 2 * wcnt;
        for (int t = wave; t < ntask; t += NWAVES) {
            const int row = t >> 1, ch = t & 1;
            float4 rb = s_bs[row];
            float area_r =
                __fmul_rn(__fsub_rn(rb.z, rb.x), __fsub_rn(rb.w, rb.y));
            int colj = ch * 64 + lane;
            bool s = (colj < wcnt) &&
                     iou_gt(rb.x, rb.y, rb.z, rb.w, area_r, s_bs[colj]);
            unsigned long long m = __ballot(s);
            if (lane == 0) s_mask[row][ch] = m;
        }
    }
    __syncthreads();

    // ---- Phase D3: serial resolve (wave 0, all lanes lockstep; pure
    // bit-ops + one broadcast ds_read_b128 per kept box).
    if (wave == 0 && !overflow) {
        unsigned long long a0, a1;
        if (wcnt >= 64) {
            a0 = ~0ull;
            a1 = (wcnt >= 128) ? ~0ull
                               : ((wcnt > 64) ? ((1ull << (wcnt - 64)) - 1)
                                              : 0ull);
        } else {
            a0 = (wcnt > 0) ? ((1ull << wcnt) - 1) : 0ull;
            a1 = 0ull;
        }
        int nkept = 0;
        while ((a0 | a1) != 0 && nkept < MAX_BOXES) {
            int pos = a0 ? __builtin_ctzll(a0)
                         : 64 + __builtin_ctzll(a1);
            if (lane == 0)
                s_out[nkept] =
                    (int)(0xFFFFFFFFu - (unsigned int)s_ks[pos]);
            ++nkept;
            ulonglong2 m = *(const ulonglong2*)&s_mask[pos][0];
            a0 &= ~m.x;
            a1 &= ~m.y;
            // insurance vs infinite loop (self-IoU is 1 > T, but be safe):
            if (pos < 64) a0 &= ~(1ull << pos);
            else a1 &= ~(1ull << (pos - 64));
        }
        if (lane == 0) s_nsel = nkept;
    }
    __syncthreads();

    // ---- Phase E: exact fallback (window exhausted early / overflow).
    // Invariant: if !overflow and nsel0 < 20, every window member was
    // examined (kept or suppressed) -> all dead; non-members re-checked
    // against the selected set. Never triggers on typical data.
    const int nsel0 = s_nsel;
    const bool needs_more =
        (nsel0 < MAX_BOXES) && (overflow || (wcnt < s_total));
    if (needs_more) {
#define LIVE_K(k)                                                        \
        if (k_##k != 0) {                                                \
            bool dead =                                                  \
                (!overflow &&                                            \
                 ((unsigned int)(k_##k >> 32) >= tbits));                \
            if (!dead && nsel0 > 0) {                                    \
                int i = tid + (k)*NT;                                    \
                float4 bi = boxes4[i];                                   \
                for (int j = 0; j < nsel0; ++j) {                        \
                    float4 sb = boxes4[s_out[j]];                        \
                    float aj = __fmul_rn(__fsub_rn(sb.z, sb.x),          \
                                         __fsub_rn(sb.w, sb.y));         \
                    if (iou_gt(sb.x, sb.y, sb.z, sb.w, aj, bi)) {        \
                        dead = true;                                     \
                        break;                                           \
                    }                                                    \
                }                                                        \
            }                                                            \
            if (dead) k_##k = 0;                                         \
        }
        FOR_K(LIVE_K)
#undef LIVE_K
        for (int slot = nsel0; slot < MAX_BOXES; ++slot) {
            unsigned long long bk = 0;
#define MAXK_K(k) if (k_##k > bk) bk = k_##k;
            FOR_K(MAXK_K)
#undef MAXK_K
            #pragma unroll
            for (int off = 32; off >= 1; off >>= 1) {
                unsigned long long o =
                    (unsigned long long)__shfl_xor((long long)bk, off);
                if (o > bk) bk = o;
            }
            const int par = slot & 1;
            if (lane == 0) s_rk[par][wave] = bk;
            __syncthreads();
            unsigned long long f = s_rk[par][0];
            #pragma unroll
            for (int w = 1; w < NWAVES; ++w) {
                unsigned long long o = s_rk[par][w];
                if (o > f) f = o;
            }
            if (f == 0) break;  // uniform
            const int widx = (int)(0xFFFFFFFFu - (unsigned int)f);
            if (tid == 0) s_out[slot] = widx;
            float4 wb = boxes4[widx];  // uniform L1 broadcast
            const float area_j =
                __fmul_rn(__fsub_rn(wb.z, wb.x), __fsub_rn(wb.w, wb.y));
#define SCANE_K(k)                                                      \
            if (k_##k != 0) {                                           \
                int i = tid + (k)*NT;                                   \
                float4 b = boxes4[i];                                   \
                if (i == widx ||                                        \
                    iou_gt(wb.x, wb.y, wb.z, wb.w, area_j, b))          \
                    k_##k = 0;                                          \
            }
            FOR_K(SCANE_K)
#undef SCANE_K
        }
    }

    // ---- emit rows ----
    __syncthreads();
    if (tid < MAX_BOXES) {
        int bi = s_out[tid];
        int o = OUT_OFF_NMS + c * MAX_BOXES * 3 + tid * 3;
        if (bi >= 0) {
            out[o + 0] = 0.0f;
            out[o + 1] = (float)c;
            out[o + 2] = (float)bi;
        } else {
            out[o + 0] = -1.0f;
            out[o + 1] = -1.0f;
            out[o + 2] = -1.0f;
        }
    }
}

extern "C" void kernel_launch(void* const* d_in, const int* in_sizes, int n_in,
                              void* d_out, int out_size, void* d_ws,
                              size_t ws_size, hipStream_t stream) {
    const float* boxes = (const float*)d_in[0];   // [N,4] fp32
    const float* scores = (const float*)d_in[1];  // [N,C] fp32
    float* out = (float*)d_out;

    // Single cooperative dispatch: coalesced transpose phase, grid-wide
    // sync, then per-class NMS on the transposed columns. 173 blocks of
    // 1024 threads = 1 block/CU -> co-resident on 256 CUs.
    void* args[] = {(void*)&boxes, (void*)&scores, (void*)&out};
    hipLaunchCooperativeKernel((const void*)fused_coop_kernel,
                               dim3(GRID_BLOCKS), dim3(NT), args, 0, stream);
}

// Round 3
// 71.327 us; speedup vs baseline: 1.6068x; 1.6068x over previous
//
#include <hip/hip_runtime.h>
#include <math.h>

#define N_BOXES 10647
#define NUM_CLASSES 80
#define MAX_BOXES 20
#define IOU_T 0.1f
#define SCORE_T 0.3f

// R16: fixed window threshold. scores ~ U[0,1): E[wcnt] = 10647*0.008 = 85,
// sd 9.2. P(wcnt > 128) ~ 1e-6/class; window-exhaust-before-20-keeps
// negligible (pairwise IoU>0.1 prob ~0.9% -> ~48 picks available). Any
// violation -> exact Phase E fallback (correct, just slow).
#define WND_T 0.992f

#define NT 1024
#define NWAVES (NT / 64)
#define WCAP 128   // window capacity (LDS)

// Kernel-1 tiling: 64-row transpose tiles + boxes-copy blocks.
#define TROWS 64
#define TBLOCKS 167     // ceil(10647 / 64)
#define CPBLOCKS 6
#define K1_BLOCKS (TBLOCKS + CPBLOCKS)

// Workspace slot array: per (class, tile) a deterministic 8-slot region of
// u64 keys. Every slot is WRITTEN by k1 (zeros for empty) -> poison-safe,
// no atomics, no memset. >8 candidates in one tile (P ~ 4e-6/run) -> lane0
// writes SENTINEL -> k2 treats as overflow -> exact Phase E.
#define WSLOTS 8
#define SLOT_N (TBLOCKS * WSLOTS)   // 1336 slots per class
#define SENTINEL (~0ull)

// Output layout (all float32, concatenated):
//   [0)      boxes copy        N_BOXES*4               = 42588
//   [42588)  scores transposed NUM_CLASSES*N_BOXES     = 851760
//   [894348) nms_final         NUM_CLASSES*MAX_BOXES*3 = 4800
#define OUT_OFF_SCORES (N_BOXES * 4)
#define OUT_OFF_NMS (N_BOXES * 4 + NUM_CLASSES * N_BOXES)

// R15 post-mortem: coop kernel counters showed ~95% idle latency (VALUBusy
// 3.9%, traffic ~= model). The cost is the per-class serial phase chain.
// R16 kills k2's Phase A scan + histogram + Phase B entirely: k1 (which has
// every score in LDS anyway) pre-compacts window candidates (score>=WND_T)
// into per-(class,tile) slots; k2's main path reads 10.7 KB of slots,
// sorts, builds the suppression bit-matrix, resolves. Exact fallback kept.
#define FOR_K(OP) OP(0) OP(1) OP(2) OP(3) OP(4) OP(5) OP(6) OP(7) OP(8) OP(9) OP(10)

// Reference-exact IoU>T test (individually rounded float32 ops; inter==0 =>
// reference IoU is 0 => not suppressed, divide skipped). First box is the
// SELECTED box (reference's area1 = selected's area, added first).
__device__ __forceinline__ bool iou_gt(float jy1, float jx1, float jy2,
                                       float jx2, float area_j, float4 b) {
    float ty = fmaxf(jy1, b.x);
    float tx = fmaxf(jx1, b.y);
    float by = fminf(jy2, b.z);
    float bx = fminf(jx2, b.w);
    float dy = fmaxf(__fsub_rn(by, ty), 0.0f);
    float dx = fmaxf(__fsub_rn(bx, tx), 0.0f);
    float inter = __fmul_rn(dy, dx);
    if (!(inter > 0.0f)) return false;
    float area_i = __fmul_rn(__fsub_rn(b.z, b.x), __fsub_rn(b.w, b.y));
    float uni = __fsub_rn(__fadd_rn(area_j, area_i), inter);
    float iou = (uni > 0.0f) ? __fdiv_rn(inter, uni) : 0.0f;
    return iou > IOU_T;
}

// ---------------------------------------------------------------------------
// Kernel 1: coalesced transpose of scores [N,C]->[C,N] into out, + boxes
// copy, + per-(class,tile) window-candidate slot writes into ws.
// ---------------------------------------------------------------------------
__global__ __launch_bounds__(NT) void transpose_slots_kernel(
    const float* __restrict__ boxes, const float* __restrict__ scores,
    float* __restrict__ out, unsigned long long* __restrict__ ws) {
    const int tid = threadIdx.x;
    const int b = blockIdx.x;

    if (b >= TBLOCKS) {
        // ---- boxes copy: 10647 float4s, coalesced both sides. Also warms
        // L3 with boxes before k2's random gathers.
        for (int q = (b - TBLOCKS) * NT + tid; q < N_BOXES;
             q += CPBLOCKS * NT) {
            ((float4*)out)[q] = ((const float4*)boxes)[q];
        }
        return;
    }

    // ---- one 64-row x 80-col tile ----
    __shared__ float lds[TROWS * 81];  // [r][c], pad 81 -> conflict-free
    const int r0 = b * TROWS;
    const int nr = min(TROWS, N_BOXES - r0);

    // Read: contiguous chunk scores[r0*80 .. (r0+nr)*80), float4 loads.
    const int nq = nr * 20;  // 80 floats/row = 20 float4/row
    for (int q = tid; q < nq; q += NT) {
        const int r = q / 20;
        const int c4 = (q - r * 20) * 4;
        float4 v = *(const float4*)(scores + (r0 + r) * NUM_CLASSES + c4);
        float* dst = &lds[r * 81 + c4];
        dst[0] = v.x;
        dst[1] = v.y;
        dst[2] = v.z;
        dst[3] = v.w;
    }
    __syncthreads();

    // Write phase: wave chi owns classes {p*16+chi}; lane = row. Per class:
    // (a) transposed-column store (64 consecutive rows = 256 B contiguous),
    // (b) window-candidate ballot -> rank-compacted slot writes.
    const int r = tid & (TROWS - 1);   // lane
    const int chi = tid >> 6;          // wave 0..15
    #pragma unroll
    for (int p = 0; p < 5; ++p) {
        const int c = p * 16 + chi;
        float v = 0.0f;
        if (r < nr) {
            v = lds[r * 81 + c];
            out[OUT_OFF_SCORES + c * N_BOXES + r0 + r] = v;
        }
        const bool cand = (r < nr) && (v >= WND_T);
        const unsigned long long mask = __ballot(cand);
        unsigned long long* slot = ws + ((size_t)c * TBLOCKS + b) * WSLOTS;
        const int cnt = __popcll(mask);
        if (cnt <= WSLOTS) {
            if (cand) {
                const int rank =
                    __popcll(mask & ((1ull << r) - 1ull));
                slot[rank] =
                    ((unsigned long long)__float_as_uint(v) << 32) |
                    (0xFFFFFFFFu - (unsigned)(r0 + r));
            }
            if (r >= cnt && r < WSLOTS) slot[r] = 0ull;
        } else {
            // pathological tie burst: sentinel -> k2 overflow -> Phase E
            if (r == 0) slot[0] = SENTINEL;
            if (r >= 1 && r < WSLOTS) slot[r] = 0ull;
        }
    }
}

// ---------------------------------------------------------------------------
// Kernel 2: per-class NMS from pre-compacted slots. Main path never scans
// the score column; Phase E (exact fallback) re-scans the transposed column
// written by kernel 1.
// ---------------------------------------------------------------------------
__global__ __launch_bounds__(NT) void nms_kernel(
    const float* __restrict__ boxes, float* __restrict__ out,
    const unsigned long long* __restrict__ ws) {
    const int tid = threadIdx.x;
    const int c = blockIdx.x;
    const int wave = tid >> 6;
    const int lane = tid & 63;
    const float4* boxes4 = (const float4*)boxes;
    const float* col = out + OUT_OFF_SCORES + c * N_BOXES;  // Phase E only

    __shared__ unsigned long long s_k[WCAP];        // window keys (unsorted)
    __shared__ float4 s_b4[WCAP];                   // window boxes (unsorted)
    __shared__ unsigned long long s_ks[WCAP];       // sorted keys
    __shared__ float4 s_bs[WCAP];                   // sorted boxes
    __shared__ __align__(16) unsigned long long s_mask[WCAP][2];  // 2 KB
    __shared__ unsigned long long s_rk[2][NWAVES];  // fallback reduce
    __shared__ int s_out[MAX_BOXES];
    __shared__ int s_cnt, s_nsel, s_ovf;

    if (tid < MAX_BOXES) s_out[tid] = -1;
    if (tid == 0) { s_cnt = 0; s_nsel = 0; s_ovf = 0; }
    __syncthreads();

    // ---- Phase C': slot scan (10.7 KB coalesced) -> compact window ----
    const unsigned long long* wsl = ws + (size_t)c * SLOT_N;
    for (int q = tid; q < SLOT_N; q += NT) {
        unsigned long long s = wsl[q];
        bool val = false;
        if (s != 0ull) {
            if ((unsigned)(s >> 32) >= 0x3F800000u) {
                s_ovf = 1;  // sentinel (benign LDS race, same value)
            } else {
                val = true;
            }
        }
        const unsigned long long m = __ballot(val);
        int basew = 0;
        if (lane == 0 && m) basew = atomicAdd(&s_cnt, __popcll(m));
        basew = __shfl(basew, 0);
        if (val) {
            const int pos = basew + __popcll(m & ((1ull << lane) - 1ull));
            if (pos < WCAP) {
                s_k[pos] = s;
                s_b4[pos] = boxes4[0xFFFFFFFFu - (unsigned)s];
            }
        }
    }
    __syncthreads();

    const int wcnt = s_cnt;
    const bool overflow = (wcnt > WCAP) || (s_ovf != 0);

    // ---- Phase D1: parallel rank sort of the window (threads 0..wcnt).
    // rank_i = #{j : key_j > key_i}; keys unique -> permutation.
    if (!overflow && tid < wcnt) {
        const unsigned long long mykey = s_k[tid];
        const float4 mybox = s_b4[tid];
        int rank = 0;
        for (int j = 0; j < wcnt; ++j) rank += (s_k[j] > mykey) ? 1 : 0;
        s_ks[rank] = mykey;
        s_bs[rank] = mybox;
    }
    __syncthreads();

    // ---- Phase D2: parallel suppression bit-matrix. Task t = (row,chunk):
    // lane computes iou_gt(row, chunk*64+lane); one ballot per task.
    // Row = selected-box role (reference op order).
    if (!overflow) {
        const int ntask = 2 * wcnt;
        for (int t = wave; t < ntask; t += NWAVES) {
            const int row = t >> 1, ch = t & 1;
            float4 rb = s_bs[row];
            float area_r =
                __fmul_rn(__fsub_rn(rb.z, rb.x), __fsub_rn(rb.w, rb.y));
            int colj = ch * 64 + lane;
            bool s = (colj < wcnt) &&
                     iou_gt(rb.x, rb.y, rb.z, rb.w, area_r, s_bs[colj]);
            unsigned long long m = __ballot(s);
            if (lane == 0) s_mask[row][ch] = m;
        }
    }
    __syncthreads();

    // ---- Phase D3: serial resolve (wave 0, lockstep; pure bit-ops + one
    // broadcast ds_read_b128 per kept box).
    if (wave == 0 && !overflow) {
        unsigned long long a0, a1;
        if (wcnt >= 64) {
            a0 = ~0ull;
            a1 = (wcnt >= 128) ? ~0ull
                               : ((wcnt > 64) ? ((1ull << (wcnt - 64)) - 1)
                                              : 0ull);
        } else {
            a0 = (wcnt > 0) ? ((1ull << wcnt) - 1) : 0ull;
            a1 = 0ull;
        }
        int nkept = 0;
        while ((a0 | a1) != 0 && nkept < MAX_BOXES) {
            int pos = a0 ? __builtin_ctzll(a0)
                         : 64 + __builtin_ctzll(a1);
            if (lane == 0)
                s_out[nkept] =
                    (int)(0xFFFFFFFFu - (unsigned int)s_ks[pos]);
            ++nkept;
            ulonglong2 m = *(const ulonglong2*)&s_mask[pos][0];
            a0 &= ~m.x;
            a1 &= ~m.y;
            if (pos < 64) a0 &= ~(1ull << pos);
            else a1 &= ~(1ull << (pos - 64));
        }
        if (lane == 0) s_nsel = nkept;
    }
    __syncthreads();

    // ---- Phase E: exact fallback (window exhausted early / overflow).
    // Invariant: if !overflow and nsel0 < 20, every window member (score >=
    // WND_T) was examined (kept or suppressed) -> all dead; others checked
    // against the selected set. Never triggers on typical data.
    const int nsel0 = s_nsel;
    const bool needs_more = (nsel0 < MAX_BOXES);
    if (needs_more) {
#define DECL_K(k) unsigned long long k_##k = 0;
        FOR_K(DECL_K)
#undef DECL_K
#define BUILDE_K(k)                                                      \
        {                                                                \
            int i = tid + (k)*NT;                                        \
            if (i < N_BOXES) {                                           \
                float v = col[i];                                        \
                if (v >= SCORE_T) {                                      \
                    bool dead = (!overflow && v >= WND_T);               \
                    if (!dead && nsel0 > 0) {                            \
                        float4 bi = boxes4[i];                           \
                        for (int j = 0; j < nsel0; ++j) {                \
                            float4 sb = boxes4[s_out[j]];                \
                            float aj =                                   \
                                __fmul_rn(__fsub_rn(sb.z, sb.x),         \
                                          __fsub_rn(sb.w, sb.y));        \
                            if (iou_gt(sb.x, sb.y, sb.z, sb.w, aj,       \
                                       bi)) {                            \
                                dead = true;                             \
                                break;                                   \
                            }                                            \
                        }                                                \
                    }                                                    \
                    if (!dead)                                           \
                        k_##k = ((unsigned long long)__float_as_uint(v)  \
                                 << 32) |                                \
                                (0xFFFFFFFFu - (unsigned int)i);         \
                }                                                        \
            }                                                            \
        }
        FOR_K(BUILDE_K)
#undef BUILDE_K
        for (int slot = nsel0; slot < MAX_BOXES; ++slot) {
            unsigned long long bk = 0;
#define MAXK_K(k) if (k_##k > bk) bk = k_##k;
            FOR_K(MAXK_K)
#undef MAXK_K
            #pragma unroll
            for (int off = 32; off >= 1; off >>= 1) {
                unsigned long long o =
                    (unsigned long long)__shfl_xor((long long)bk, off);
                if (o > bk) bk = o;
            }
            const int par = slot & 1;
            if (lane == 0) s_rk[par][wave] = bk;
            __syncthreads();
            unsigned long long f = s_rk[par][0];
            #pragma unroll
            for (int w = 1; w < NWAVES; ++w) {
                unsigned long long o = s_rk[par][w];
                if (o > f) f = o;
            }
            if (f == 0) break;  // uniform
            const int widx = (int)(0xFFFFFFFFu - (unsigned int)f);
            if (tid == 0) s_out[slot] = widx;
            float4 wb = boxes4[widx];  // uniform L1 broadcast
            const float area_j =
                __fmul_rn(__fsub_rn(wb.z, wb.x), __fsub_rn(wb.w, wb.y));
#define SCANE_K(k)                                                      \
            if (k_##k != 0) {                                           \
                int i = tid + (k)*NT;                                   \
                float4 b = boxes4[i];                                   \
                if (i == widx ||                                        \
                    iou_gt(wb.x, wb.y, wb.z, wb.w, area_j, b))          \
                    k_##k = 0;                                          \
            }
            FOR_K(SCANE_K)
#undef SCANE_K
        }
    }

    // ---- emit rows ----
    __syncthreads();
    if (tid < MAX_BOXES) {
        int bi = s_out[tid];
        int o = OUT_OFF_NMS + c * MAX_BOXES * 3 + tid * 3;
        if (bi >= 0) {
            out[o + 0] = 0.0f;
            out[o + 1] = (float)c;
            out[o + 2] = (float)bi;
        } else {
            out[o + 0] = -1.0f;
            out[o + 1] = -1.0f;
            out[o + 2] = -1.0f;
        }
    }
}

extern "C" void kernel_launch(void* const* d_in, const int* in_sizes, int n_in,
                              void* d_out, int out_size, void* d_ws,
                              size_t ws_size, hipStream_t stream) {
    const float* boxes = (const float*)d_in[0];   // [N,4] fp32
    const float* scores = (const float*)d_in[1];  // [N,C] fp32
    float* out = (float*)d_out;
    unsigned long long* ws = (unsigned long long*)d_ws;  // 855 KB slots

    // Launch 1: transpose (+ boxes copy) + window-candidate slot writes.
    transpose_slots_kernel<<<K1_BLOCKS, NT, 0, stream>>>(boxes, scores, out,
                                                         ws);
    // Launch 2: NMS from pre-compacted slots (exact fallback kept).
    nms_kernel<<<NUM_CLASSES, NT, 0, stream>>>(boxes, out, ws);
}